// Round 1
// baseline (299.388 us; speedup 1.0000x reference)
//
#include <hip/hip_runtime.h>
#include <math.h>

#define BB 2048
#define SS 32
#define KK 1024
#define DD 64
#define BS (BB*SS)            // 65536 rows
#define TM 16                 // rows per block
#define NBLK (BS/TM)          // 4096 blocks
#define LN_2PI 1.8378770664093453f
#define DECAY 0.9f

// ws layout in floats:
//   [WT_OFF,   +128*1024)  W_t[dd][k]: dd<64 -> -0.5*inv_var[k][dd], dd>=64 -> mu*inv_var
//   [C_OFF,    +1024)      c[k] = -0.5*m2[k] - sum(log_sigma[k]) - 0.5*D*ln(2pi)
//   [SIG_OFF,  +65536)     sigma[k][d]
//   [RESP_OFF, +1024)      resp_sum[k] accumulator (zeroed each launch)
#define WT_OFF   0
#define C_OFF    (128*1024)
#define SIG_OFF  (C_OFF + 1024)
#define RESP_OFF (SIG_OFF + KK*DD)

__global__ __launch_bounds__(64) void prep_kernel(
    const float* __restrict__ mu, const float* __restrict__ log_sigma,
    float* __restrict__ ws) {
  int k = blockIdx.x;
  int d = threadIdx.x;
  float ls = log_sigma[k*DD + d];
  float m  = mu[k*DD + d];
  float iv = expf(-2.0f*ls);
  ws[WT_OFF + d*KK + k]        = -0.5f*iv;
  ws[WT_OFF + (64+d)*KK + k]   = m*iv;
  ws[SIG_OFF + k*DD + d]       = expf(ls);
  float t1 = m*m*iv;
  float t2 = ls;
  #pragma unroll
  for (int off = 32; off; off >>= 1) {
    t1 += __shfl_xor(t1, off);
    t2 += __shfl_xor(t2, off);
  }
  if (d == 0) ws[C_OFF + k] = -0.5f*t1 - t2 - 32.0f*LN_2PI;
}

__global__ __launch_bounds__(256) void main_kernel(
    const float* __restrict__ slots, const float* __restrict__ mu,
    const float* __restrict__ z, const float* __restrict__ ws,
    float* __restrict__ out_slots, float* __restrict__ out_ll,
    float* __restrict__ resp_g) {
  __shared__ float A_l[128][TM];      // [dd][r] : dd<64 -> s^2, dd>=64 -> s
  __shared__ float resp_l[4][KK];     // per-wave resp partials
  __shared__ int   am_l[TM];          // per-row argmax

  const int t    = threadIdx.x;
  const int lane = t & 63;
  const int wave = t >> 6;
  const int blk  = blockIdx.x;
  const int R0   = blk * TM;

  // ---- stage A (s^2 ; s), transposed [dd][row] ----
  {
    int row  = t >> 4;          // 0..15
    int dpos = (t & 15) * 4;    // 0,4,...,60
    float4 v = *(const float4*)(slots + (size_t)(R0 + row)*DD + dpos);
    A_l[dpos+0][row] = v.x*v.x;  A_l[64+dpos+0][row] = v.x;
    A_l[dpos+1][row] = v.y*v.y;  A_l[64+dpos+1][row] = v.y;
    A_l[dpos+2][row] = v.z*v.z;  A_l[64+dpos+2][row] = v.z;
    A_l[dpos+3][row] = v.w*v.w;  A_l[64+dpos+3][row] = v.w;
  }
  __syncthreads();

  // ---- GEMM: 4 rows x 16 cols per lane; cols = 256*g + 4*lane + q ----
  const float4* W4 = (const float4*)(ws + WT_OFF);
  const float4* C4 = (const float4*)(ws + C_OFF);
  float acc[4][16];
  #pragma unroll
  for (int g = 0; g < 4; ++g) {
    float4 c = C4[g*64 + lane];
    #pragma unroll
    for (int i = 0; i < 4; ++i) {
      acc[i][4*g+0] = c.x; acc[i][4*g+1] = c.y;
      acc[i][4*g+2] = c.z; acc[i][4*g+3] = c.w;
    }
  }
  const int r0 = wave * 4;
  #pragma unroll 2
  for (int dd = 0; dd < 128; ++dd) {
    float4 a4 = *(const float4*)&A_l[dd][r0];
    float a[4] = {a4.x, a4.y, a4.z, a4.w};
    #pragma unroll
    for (int g = 0; g < 4; ++g) {
      float4 w = W4[dd*256 + g*64 + lane];
      #pragma unroll
      for (int i = 0; i < 4; ++i) {
        acc[i][4*g+0] = fmaf(a[i], w.x, acc[i][4*g+0]);
        acc[i][4*g+1] = fmaf(a[i], w.y, acc[i][4*g+1]);
        acc[i][4*g+2] = fmaf(a[i], w.z, acc[i][4*g+2]);
        acc[i][4*g+3] = fmaf(a[i], w.w, acc[i][4*g+3]);
      }
    }
  }

  // ---- per-row: max/argmax (lower index wins), denom, resp, ll ----
  float resp_acc[16];
  #pragma unroll
  for (int q = 0; q < 16; ++q) resp_acc[q] = 0.0f;

  #pragma unroll
  for (int i = 0; i < 4; ++i) {
    float m = acc[i][0];
    int   mi = (lane << 2);            // col(q=0)
    #pragma unroll
    for (int q = 1; q < 16; ++q) {
      int col = ((q >> 2) << 8) + (lane << 2) + (q & 3);
      if (acc[i][q] > m) { m = acc[i][q]; mi = col; }
    }
    #pragma unroll
    for (int off = 1; off < 64; off <<= 1) {
      float om = __shfl_xor(m, off);
      int   oi = __shfl_xor(mi, off);
      if (om > m || (om == m && oi < mi)) { m = om; mi = oi; }
    }
    float s = 0.0f;
    #pragma unroll
    for (int q = 0; q < 16; ++q) s += __expf(acc[i][q] - m);
    #pragma unroll
    for (int off = 1; off < 64; off <<= 1) s += __shfl_xor(s, off);
    float inv_den = 1.0f / s;
    #pragma unroll
    for (int q = 0; q < 16; ++q)
      resp_acc[q] += __expf(acc[i][q] - m) * inv_den;
    if (lane == 0) {
      int row = r0 + i;
      out_ll[R0 + row] = m;            // log_likelihood = lp at argmax = max
      am_l[row] = mi;
    }
  }
  #pragma unroll
  for (int g = 0; g < 4; ++g) {
    float4 v = make_float4(resp_acc[4*g+0], resp_acc[4*g+1],
                           resp_acc[4*g+2], resp_acc[4*g+3]);
    *(float4*)&resp_l[wave][(g << 8) + (lane << 2)] = v;
  }
  __syncthreads();

  // ---- block resp -> global atomic ----
  for (int c = t; c < KK; c += 256) {
    float s = resp_l[0][c] + resp_l[1][c] + resp_l[2][c] + resp_l[3][c];
    atomicAdd(resp_g + c, s);
  }

  // ---- new_slots: mu[a] + sigma[a]*z ----
  {
    int row  = t >> 4;
    int dpos = (t & 15) * 4;
    int a = am_l[row];
    float4 zv = *(const float4*)(z  + (size_t)(R0 + row)*DD + dpos);
    float4 mv = *(const float4*)(mu + (size_t)a*DD + dpos);
    float4 sg = *(const float4*)(ws + SIG_OFF + (size_t)a*DD + dpos);
    float4 o;
    o.x = fmaf(sg.x, zv.x, mv.x);
    o.y = fmaf(sg.y, zv.y, mv.y);
    o.z = fmaf(sg.z, zv.z, mv.z);
    o.w = fmaf(sg.w, zv.w, mv.w);
    *(float4*)(out_slots + (size_t)(R0 + row)*DD + dpos) = o;
  }
}

__device__ __forceinline__ float block_max_1024(float v, float* red) {
  #pragma unroll
  for (int off = 32; off; off >>= 1) v = fmaxf(v, __shfl_xor(v, off));
  int wave = threadIdx.x >> 6, lane = threadIdx.x & 63;
  if (lane == 0) red[wave] = v;
  __syncthreads();
  float m = red[0];
  #pragma unroll
  for (int w = 1; w < 16; ++w) m = fmaxf(m, red[w]);
  __syncthreads();
  return m;
}

__device__ __forceinline__ float block_sum_1024(float v, float* red) {
  #pragma unroll
  for (int off = 32; off; off >>= 1) v += __shfl_xor(v, off);
  int wave = threadIdx.x >> 6, lane = threadIdx.x & 63;
  if (lane == 0) red[wave] = v;
  __syncthreads();
  float s = 0.0f;
  #pragma unroll
  for (int w = 0; w < 16; ++w) s += red[w];
  __syncthreads();
  return s;
}

__global__ __launch_bounds__(1024) void finalize_kernel(
    const float* __restrict__ log_prior, const float* __restrict__ resp_g,
    float* __restrict__ out_prior) {
  __shared__ float red[16];
  int t = threadIdx.x;
  float lp = log_prior[t];
  float rs = resp_g[t];

  float m1 = block_max_1024(lp, red);
  float e1 = __expf(lp - m1);
  float s1 = block_sum_1024(e1, red);

  float m2 = block_max_1024(rs, red);
  float e2 = __expf(rs - m2);
  float s2 = block_sum_1024(e2, red);

  out_prior[t] = DECAY * (e1 / s1) + (1.0f - DECAY) * (e2 / s2);
}

extern "C" void kernel_launch(void* const* d_in, const int* in_sizes, int n_in,
                              void* d_out, int out_size, void* d_ws, size_t ws_size,
                              hipStream_t stream) {
  const float* slots     = (const float*)d_in[0];
  const float* mu        = (const float*)d_in[1];
  const float* log_sigma = (const float*)d_in[2];
  const float* log_prior = (const float*)d_in[3];
  const float* z         = (const float*)d_in[4];

  float* out       = (float*)d_out;
  float* out_slots = out;                       // [BS*DD]
  float* out_ll    = out + (size_t)BS*DD;       // [BS]
  float* out_prior = out + (size_t)BS*DD + BS;  // [KK]
  float* ws        = (float*)d_ws;

  hipMemsetAsync(ws + RESP_OFF, 0, KK*sizeof(float), stream);
  prep_kernel<<<KK, 64, 0, stream>>>(mu, log_sigma, ws);
  main_kernel<<<NBLK, 256, 0, stream>>>(slots, mu, z, ws, out_slots, out_ll,
                                        ws + RESP_OFF);
  finalize_kernel<<<1, 1024, 0, stream>>>(log_prior, ws + RESP_OFF, out_prior);
}

// Round 2
// 282.145 us; speedup vs baseline: 1.0611x; 1.0611x over previous
//
#include <hip/hip_runtime.h>
#include <math.h>

#define BB 2048
#define SS 32
#define KK 1024
#define DD 64
#define BS (BB*SS)            // 65536 rows
#define TM 16                 // rows per block
#define NBLK (BS/TM)          // 4096 blocks
#define LN_2PI 1.8378770664093453f
#define DECAY 0.9f

// ws layout in floats:
//   [WT_OFF,   +128*1024)  W_t[dd][k]: dd<64 -> -0.5*inv_var[k][dd], dd>=64 -> mu*inv_var
//   [C_OFF,    +1024)      c[k] = -0.5*m2[k] - sum(log_sigma[k]) - 0.5*D*ln(2pi)
//   [SIG_OFF,  +65536)     sigma[k][d]
//   [RESP_OFF, +1024)      resp_sum[k] accumulator (zeroed each launch)
#define WT_OFF   0
#define C_OFF    (128*1024)
#define SIG_OFF  (C_OFF + 1024)
#define RESP_OFF (SIG_OFF + KK*DD)

__global__ __launch_bounds__(64) void prep_kernel(
    const float* __restrict__ mu, const float* __restrict__ log_sigma,
    float* __restrict__ ws) {
  int k = blockIdx.x;
  int d = threadIdx.x;
  float ls = log_sigma[k*DD + d];
  float m  = mu[k*DD + d];
  float iv = expf(-2.0f*ls);
  ws[WT_OFF + d*KK + k]        = -0.5f*iv;
  ws[WT_OFF + (64+d)*KK + k]   = m*iv;
  ws[SIG_OFF + k*DD + d]       = expf(ls);
  float t1 = m*m*iv;
  float t2 = ls;
  #pragma unroll
  for (int off = 32; off; off >>= 1) {
    t1 += __shfl_xor(t1, off);
    t2 += __shfl_xor(t2, off);
  }
  if (d == 0) ws[C_OFF + k] = -0.5f*t1 - t2 - 32.0f*LN_2PI;
}

// 256 threads = 4 waves. Wave cg owns cols [cg*256, cg*256+256).
// Each lane: 16 rows x 4 cols accumulator tile (cols = cg*256 + lane*4 + q).
// Per dq step: 64 B of W per lane, 256 FMA -> 8 FLOP/B on L2.
__global__ __launch_bounds__(256, 4) void main_kernel(
    const float* __restrict__ slots, const float* __restrict__ mu,
    const float* __restrict__ z, const float* __restrict__ ws,
    float* __restrict__ out_slots, float* __restrict__ out_ll,
    float* __restrict__ resp_g) {
  __shared__ float A2[TM][128];     // [row][dd]: dd<64 -> s^2, dd>=64 -> s
  __shared__ float mxl[TM][4];      // per-(row,cg) partial max
  __shared__ int   ail[TM][4];      // per-(row,cg) partial argmax
  __shared__ float sml[TM][4];      // per-(row,cg) partial exp-sum
  __shared__ float resl[KK];        // per-block resp (cols partitioned by cg)
  __shared__ int   am_l[TM];        // per-row argmax

  const int t    = threadIdx.x;
  const int lane = t & 63;
  const int cg   = t >> 6;          // wave == col group
  const int R0   = blockIdx.x * TM;
  const int base_col = (cg << 8) + (lane << 2);

  // ---- stage A row-major: contiguous LDS writes (conflict-free),
  //      GEMM reads are same-address broadcasts (conflict-immune) ----
  {
    int row  = t >> 4;              // 0..15
    int dpos = (t & 15) * 4;        // 0..60
    float4 v = *(const float4*)(slots + (size_t)(R0 + row)*DD + dpos);
    float4 sq = make_float4(v.x*v.x, v.y*v.y, v.z*v.z, v.w*v.w);
    *(float4*)&A2[row][dpos]      = sq;
    *(float4*)&A2[row][64 + dpos] = v;
  }
  __syncthreads();

  // ---- GEMM: acc[row 0..15][col q 0..3] ----
  const float4* Wp = (const float4*)(ws + WT_OFF) + (cg << 6) + lane;
  const float4* C4 = (const float4*)(ws + C_OFF);
  float acc[16][4];
  {
    float4 c = C4[(cg << 6) + lane];
    #pragma unroll
    for (int r = 0; r < 16; ++r) {
      acc[r][0] = c.x; acc[r][1] = c.y; acc[r][2] = c.z; acc[r][3] = c.w;
    }
  }
  for (int dq = 0; dq < 32; ++dq) {
    float4 w[4];
    #pragma unroll
    for (int e = 0; e < 4; ++e) w[e] = Wp[(4*dq + e) << 8];
    #pragma unroll
    for (int r = 0; r < 16; ++r) {
      float4 a = *(const float4*)&A2[r][4*dq];
      float av[4] = {a.x, a.y, a.z, a.w};
      #pragma unroll
      for (int e = 0; e < 4; ++e) {
        acc[r][0] = fmaf(av[e], w[e].x, acc[r][0]);
        acc[r][1] = fmaf(av[e], w[e].y, acc[r][1]);
        acc[r][2] = fmaf(av[e], w[e].z, acc[r][2]);
        acc[r][3] = fmaf(av[e], w[e].w, acc[r][3]);
      }
    }
  }

  // ---- phase 1: per-wave max/argmax over this wave's 256 cols ----
  #pragma unroll
  for (int r = 0; r < 16; ++r) {
    float m = acc[r][0];
    int   mi = base_col;
    #pragma unroll
    for (int q = 1; q < 4; ++q)
      if (acc[r][q] > m) { m = acc[r][q]; mi = base_col + q; }
    #pragma unroll
    for (int off = 1; off < 64; off <<= 1) {
      float om = __shfl_xor(m, off);
      int   oi = __shfl_xor(mi, off);
      if (om > m || (om == m && oi < mi)) { m = om; mi = oi; }
    }
    if (lane == 0) { mxl[r][cg] = m; ail[r][cg] = mi; }
  }
  __syncthreads();

  // ---- phase 2: global max per row; exp in place; per-wave exp-sum ----
  float gm[16];
  {
    int gai[16];
    #pragma unroll
    for (int r = 0; r < 16; ++r) {
      float m = mxl[r][0]; int mi = ail[r][0];
      #pragma unroll
      for (int g = 1; g < 4; ++g) {
        float om = mxl[r][g]; int oi = ail[r][g];
        if (om > m || (om == m && oi < mi)) { m = om; mi = oi; }
      }
      gm[r] = m; gai[r] = mi;
    }
    if (t == 0) {
      #pragma unroll
      for (int r = 0; r < 16; ++r) {
        am_l[r] = gai[r];
        out_ll[R0 + r] = gm[r];      // ll = lp at argmax = row max
      }
    }
  }
  #pragma unroll
  for (int r = 0; r < 16; ++r) {
    float s = 0.0f;
    #pragma unroll
    for (int q = 0; q < 4; ++q) {
      acc[r][q] = __expf(acc[r][q] - gm[r]);
      s += acc[r][q];
    }
    #pragma unroll
    for (int off = 1; off < 64; off <<= 1) s += __shfl_xor(s, off);
    if (lane == 0) sml[r][cg] = s;
  }
  __syncthreads();

  // ---- phase 3: responsibilities summed over the block's 16 rows ----
  {
    float racc[4] = {0.0f, 0.0f, 0.0f, 0.0f};
    #pragma unroll
    for (int r = 0; r < 16; ++r) {
      float inv = 1.0f / (sml[r][0] + sml[r][1] + sml[r][2] + sml[r][3]);
      #pragma unroll
      for (int q = 0; q < 4; ++q) racc[q] += acc[r][q] * inv;
    }
    *(float4*)&resl[base_col] = make_float4(racc[0], racc[1], racc[2], racc[3]);
  }
  __syncthreads();

  for (int c = t; c < KK; c += 256)
    atomicAdd(resp_g + c, resl[c]);

  // ---- new_slots: mu[a] + sigma[a]*z ----
  {
    int row  = t >> 4;
    int dpos = (t & 15) * 4;
    int a = am_l[row];
    float4 zv = *(const float4*)(z  + (size_t)(R0 + row)*DD + dpos);
    float4 mv = *(const float4*)(mu + (size_t)a*DD + dpos);
    float4 sg = *(const float4*)(ws + SIG_OFF + (size_t)a*DD + dpos);
    float4 o;
    o.x = fmaf(sg.x, zv.x, mv.x);
    o.y = fmaf(sg.y, zv.y, mv.y);
    o.z = fmaf(sg.z, zv.z, mv.z);
    o.w = fmaf(sg.w, zv.w, mv.w);
    *(float4*)(out_slots + (size_t)(R0 + row)*DD + dpos) = o;
  }
}

__device__ __forceinline__ float block_max_1024(float v, float* red) {
  #pragma unroll
  for (int off = 32; off; off >>= 1) v = fmaxf(v, __shfl_xor(v, off));
  int wave = threadIdx.x >> 6, lane = threadIdx.x & 63;
  if (lane == 0) red[wave] = v;
  __syncthreads();
  float m = red[0];
  #pragma unroll
  for (int w = 1; w < 16; ++w) m = fmaxf(m, red[w]);
  __syncthreads();
  return m;
}

__device__ __forceinline__ float block_sum_1024(float v, float* red) {
  #pragma unroll
  for (int off = 32; off; off >>= 1) v += __shfl_xor(v, off);
  int wave = threadIdx.x >> 6, lane = threadIdx.x & 63;
  if (lane == 0) red[wave] = v;
  __syncthreads();
  float s = 0.0f;
  #pragma unroll
  for (int w = 0; w < 16; ++w) s += red[w];
  __syncthreads();
  return s;
}

__global__ __launch_bounds__(1024) void finalize_kernel(
    const float* __restrict__ log_prior, const float* __restrict__ resp_g,
    float* __restrict__ out_prior) {
  __shared__ float red[16];
  int t = threadIdx.x;
  float lp = log_prior[t];
  float rs = resp_g[t];

  float m1 = block_max_1024(lp, red);
  float e1 = __expf(lp - m1);
  float s1 = block_sum_1024(e1, red);

  float m2 = block_max_1024(rs, red);
  float e2 = __expf(rs - m2);
  float s2 = block_sum_1024(e2, red);

  out_prior[t] = DECAY * (e1 / s1) + (1.0f - DECAY) * (e2 / s2);
}

extern "C" void kernel_launch(void* const* d_in, const int* in_sizes, int n_in,
                              void* d_out, int out_size, void* d_ws, size_t ws_size,
                              hipStream_t stream) {
  const float* slots     = (const float*)d_in[0];
  const float* mu        = (const float*)d_in[1];
  const float* log_sigma = (const float*)d_in[2];
  const float* log_prior = (const float*)d_in[3];
  const float* z         = (const float*)d_in[4];

  float* out       = (float*)d_out;
  float* out_slots = out;                       // [BS*DD]
  float* out_ll    = out + (size_t)BS*DD;       // [BS]
  float* out_prior = out + (size_t)BS*DD + BS;  // [KK]
  float* ws        = (float*)d_ws;

  hipMemsetAsync(ws + RESP_OFF, 0, KK*sizeof(float), stream);
  prep_kernel<<<KK, 64, 0, stream>>>(mu, log_sigma, ws);
  main_kernel<<<NBLK, 256, 0, stream>>>(slots, mu, z, ws, out_slots, out_ll,
                                        ws + RESP_OFF);
  finalize_kernel<<<1, 1024, 0, stream>>>(log_prior, ws + RESP_OFF, out_prior);
}

// Round 3
// 115.935 us; speedup vs baseline: 2.5824x; 2.4337x over previous
//
#include <hip/hip_runtime.h>
#include <math.h>

#define KK 1024
#define DD 64
#define BS 65536              // 2048*32 rows
#define TM 64                 // rows per block
#define NBLK (BS/TM)          // 1024
#define NTHR 512
#define LN_2PI 1.8378770664093453f
#define DECAY 0.9f
#define APAD 136              // LDS row stride (halves): 272B -> 2-way-only conflicts, 16B aligned

typedef _Float16 f16x8 __attribute__((ext_vector_type(8)));
typedef float f32x4 __attribute__((ext_vector_type(4)));

// ws layout in FLOAT units:
//  [BH_OFF, +65536)  W_hi fp16 [16 kblk][1024 col][8 k] (131072 halves)
//  [BL_OFF, +65536)  W_lo fp16 same layout
//  [C_OFF,  +1024)   c[k]
//  [SIG_OFF,+65536)  sigma[k][d] fp32
//  [RESP_OFF,+1024)  resp accumulator
#define BH_OFF   0
#define BL_OFF   65536
#define C_OFF    131072
#define SIG_OFF  (C_OFF + KK)
#define RESP_OFF (SIG_OFF + KK*DD)

__global__ __launch_bounds__(64) void prep_kernel(
    const float* __restrict__ mu, const float* __restrict__ log_sigma,
    float* __restrict__ ws) {
  int k = blockIdx.x;
  int d = threadIdx.x;
  float ls = log_sigma[k*DD + d];
  float m  = mu[k*DD + d];
  float iv = expf(-2.0f*ls);
  _Float16* Bh = (_Float16*)(ws + BH_OFF);
  _Float16* Bl = (_Float16*)(ws + BL_OFF);
  // dd = d : coeff of s^2 ; dd = 64+d : coeff of s
  {
    float w0 = -0.5f*iv;
    _Float16 h = (_Float16)w0;
    int dd = d;
    Bh[((size_t)(dd >> 3)*KK + k)*8 + (dd & 7)] = h;
    Bl[((size_t)(dd >> 3)*KK + k)*8 + (dd & 7)] = (_Float16)(w0 - (float)h);
  }
  {
    float w1 = m*iv;
    _Float16 h = (_Float16)w1;
    int dd = 64 + d;
    Bh[((size_t)(dd >> 3)*KK + k)*8 + (dd & 7)] = h;
    Bl[((size_t)(dd >> 3)*KK + k)*8 + (dd & 7)] = (_Float16)(w1 - (float)h);
  }
  ws[SIG_OFF + k*DD + d] = expf(ls);
  float t1 = m*m*iv;
  float t2 = ls;
  #pragma unroll
  for (int off = 32; off; off >>= 1) {
    t1 += __shfl_xor(t1, off);
    t2 += __shfl_xor(t2, off);
  }
  if (d == 0) ws[C_OFF + k] = -0.5f*t1 - t2 - 32.0f*LN_2PI;
}

// 512 threads = 8 waves. Wave w owns cols [w*128, +128), all 64 rows.
// Per wave: 4 rowgroups x 8 coltiles of 16x16, K=128 = 4 slices of 32,
// 3 MFMA products per (rg,ct,slice) -> 384 MFMA.
__global__ __launch_bounds__(512, 2) void main_kernel(
    const float* __restrict__ slots, const float* __restrict__ mu,
    const float* __restrict__ z, const float* __restrict__ ws,
    float* __restrict__ out_slots, float* __restrict__ out_ll,
    float* __restrict__ resp_g) {
  __shared__ _Float16 Ah[TM][APAD];   // [row][dd]: dd<64 s^2 hi, dd>=64 s hi
  __shared__ _Float16 Al[TM][APAD];   // lo residuals
  __shared__ float mxl[TM][8];
  __shared__ int   ail[TM][8];
  __shared__ float sml[TM][8];
  __shared__ float gm_l[TM];
  __shared__ float inv_l[TM];
  __shared__ int   am_l[TM];
  __shared__ float resl[KK];

  const int t    = threadIdx.x;
  const int lane = t & 63;
  const int w    = t >> 6;           // wave = 128-col group
  const int lg   = lane >> 4;        // 0..3
  const int lc   = lane & 15;        // col-in-tile (B/C) / row (A)
  const int R0   = blockIdx.x * TM;

  // ---- stage A as pre-split fp16 hi/lo ----
  {
    int row = t >> 3;                // 0..63
    int dp  = (t & 7) * 8;           // 0..56
    float4 v0 = *(const float4*)(slots + (size_t)(R0 + row)*DD + dp);
    float4 v1 = *(const float4*)(slots + (size_t)(R0 + row)*DD + dp + 4);
    float f[8] = {v0.x, v0.y, v0.z, v0.w, v1.x, v1.y, v1.z, v1.w};
    f16x8 sqh, sql, sh, sl;
    #pragma unroll
    for (int j = 0; j < 8; ++j) {
      float sq = f[j]*f[j];
      _Float16 h1 = (_Float16)sq;
      sqh[j] = h1; sql[j] = (_Float16)(sq - (float)h1);
      _Float16 h2 = (_Float16)f[j];
      sh[j] = h2;  sl[j]  = (_Float16)(f[j] - (float)h2);
    }
    *(f16x8*)&Ah[row][dp]      = sqh;
    *(f16x8*)&Al[row][dp]      = sql;
    *(f16x8*)&Ah[row][64 + dp] = sh;
    *(f16x8*)&Al[row][64 + dp] = sl;
  }
  __syncthreads();

  // ---- MFMA GEMM ----
  const f16x8* BH = (const f16x8*)(ws + BH_OFF);
  const f16x8* BL = (const f16x8*)(ws + BL_OFF);
  const float* Cc = ws + C_OFF;
  const int colbase = (w << 7) + lc;

  f32x4 acc[4][8];
  #pragma unroll
  for (int ct = 0; ct < 8; ++ct) {
    float c = Cc[colbase + ct*16];
    #pragma unroll
    for (int rg = 0; rg < 4; ++rg) acc[rg][ct] = (f32x4){c, c, c, c};
  }

  #pragma unroll
  for (int s = 0; s < 4; ++s) {
    const int kb = s*32 + lg*8;
    f16x8 ah[4], al[4];
    #pragma unroll
    for (int rg = 0; rg < 4; ++rg) {
      ah[rg] = *(const f16x8*)&Ah[rg*16 + lc][kb];
      al[rg] = *(const f16x8*)&Al[rg*16 + lc][kb];
    }
    const int kblk = s*4 + lg;
    #pragma unroll
    for (int ct = 0; ct < 8; ++ct) {
      int col = (w << 7) + ct*16 + lc;
      f16x8 bh = BH[(size_t)kblk*KK + col];
      f16x8 bl = BL[(size_t)kblk*KK + col];
      #pragma unroll
      for (int rg = 0; rg < 4; ++rg) {
        acc[rg][ct] = __builtin_amdgcn_mfma_f32_16x16x32_f16(ah[rg], bh, acc[rg][ct], 0, 0, 0);
        acc[rg][ct] = __builtin_amdgcn_mfma_f32_16x16x32_f16(ah[rg], bl, acc[rg][ct], 0, 0, 0);
        acc[rg][ct] = __builtin_amdgcn_mfma_f32_16x16x32_f16(al[rg], bh, acc[rg][ct], 0, 0, 0);
      }
    }
  }

  // ---- phase 1: per-wave max/argmax over this wave's 128 cols ----
  // C layout: row = rg*16 + lg*4 + q, col = w*128 + ct*16 + lc
  #pragma unroll
  for (int rg = 0; rg < 4; ++rg) {
    #pragma unroll
    for (int q = 0; q < 4; ++q) {
      float m = acc[rg][0][q];
      int  mi = colbase;
      #pragma unroll
      for (int ct = 1; ct < 8; ++ct) {
        if (acc[rg][ct][q] > m) { m = acc[rg][ct][q]; mi = colbase + ct*16; }
      }
      #pragma unroll
      for (int off = 1; off < 16; off <<= 1) {
        float om = __shfl_xor(m, off);
        int   oi = __shfl_xor(mi, off);
        if (om > m || (om == m && oi < mi)) { m = om; mi = oi; }
      }
      if (lc == 0) {
        int row = rg*16 + lg*4 + q;
        mxl[row][w] = m; ail[row][w] = mi;
      }
    }
  }
  __syncthreads();

  // ---- phase 2: combine 8 waves -> global max/argmax per row ----
  if (t < TM) {
    float m = mxl[t][0]; int mi = ail[t][0];
    #pragma unroll
    for (int g = 1; g < 8; ++g) {
      float om = mxl[t][g]; int oi = ail[t][g];
      if (om > m || (om == m && oi < mi)) { m = om; mi = oi; }
    }
    gm_l[t] = m; am_l[t] = mi;
    out_ll[R0 + t] = m;                 // ll = lp at argmax = row max
  }
  __syncthreads();

  // ---- phase 3: exp in place, per-wave exp sums ----
  float gmv[4][4];
  #pragma unroll
  for (int rg = 0; rg < 4; ++rg)
    #pragma unroll
    for (int q = 0; q < 4; ++q) gmv[rg][q] = gm_l[rg*16 + lg*4 + q];

  #pragma unroll
  for (int rg = 0; rg < 4; ++rg) {
    #pragma unroll
    for (int q = 0; q < 4; ++q) {
      float sacc = 0.0f;
      #pragma unroll
      for (int ct = 0; ct < 8; ++ct) {
        float e = __expf(acc[rg][ct][q] - gmv[rg][q]);
        acc[rg][ct][q] = e;
        sacc += e;
      }
      #pragma unroll
      for (int off = 1; off < 16; off <<= 1) sacc += __shfl_xor(sacc, off);
      if (lc == 0) sml[rg*16 + lg*4 + q][w] = sacc;
    }
  }
  __syncthreads();
  if (t < TM) {
    float s = 0.0f;
    #pragma unroll
    for (int g = 0; g < 8; ++g) s += sml[t][g];
    inv_l[t] = 1.0f / s;
  }
  __syncthreads();

  // ---- phase 4: responsibilities -> per-block resl -> global atomic ----
  {
    float invv[4][4];
    #pragma unroll
    for (int rg = 0; rg < 4; ++rg)
      #pragma unroll
      for (int q = 0; q < 4; ++q) invv[rg][q] = inv_l[rg*16 + lg*4 + q];
    float rc[8];
    #pragma unroll
    for (int ct = 0; ct < 8; ++ct) {
      float s = 0.0f;
      #pragma unroll
      for (int rg = 0; rg < 4; ++rg)
        #pragma unroll
        for (int q = 0; q < 4; ++q) s += acc[rg][ct][q] * invv[rg][q];
      rc[ct] = s;
    }
    #pragma unroll
    for (int ct = 0; ct < 8; ++ct) {
      rc[ct] += __shfl_xor(rc[ct], 16);
      rc[ct] += __shfl_xor(rc[ct], 32);
    }
    if (lane < 16) {
      #pragma unroll
      for (int ct = 0; ct < 8; ++ct) resl[(w << 7) + ct*16 + lane] = rc[ct];
    }
  }
  __syncthreads();
  for (int c = t; c < KK; c += NTHR) atomicAdd(resp_g + c, resl[c]);

  // ---- new_slots: mu[a] + sigma[a]*z ----
  {
    int row = t >> 3;
    int dp  = (t & 7) * 8;
    int a = am_l[row];
    #pragma unroll
    for (int h = 0; h < 2; ++h) {
      int d0 = dp + h*4;
      float4 zv = *(const float4*)(z  + (size_t)(R0 + row)*DD + d0);
      float4 mv = *(const float4*)(mu + (size_t)a*DD + d0);
      float4 sg = *(const float4*)(ws + SIG_OFF + (size_t)a*DD + d0);
      float4 o;
      o.x = fmaf(sg.x, zv.x, mv.x);
      o.y = fmaf(sg.y, zv.y, mv.y);
      o.z = fmaf(sg.z, zv.z, mv.z);
      o.w = fmaf(sg.w, zv.w, mv.w);
      *(float4*)(out_slots + (size_t)(R0 + row)*DD + d0) = o;
    }
  }
}

__device__ __forceinline__ float block_max_1024(float v, float* red) {
  #pragma unroll
  for (int off = 32; off; off >>= 1) v = fmaxf(v, __shfl_xor(v, off));
  int wave = threadIdx.x >> 6, lane = threadIdx.x & 63;
  if (lane == 0) red[wave] = v;
  __syncthreads();
  float m = red[0];
  #pragma unroll
  for (int w = 1; w < 16; ++w) m = fmaxf(m, red[w]);
  __syncthreads();
  return m;
}

__device__ __forceinline__ float block_sum_1024(float v, float* red) {
  #pragma unroll
  for (int off = 32; off; off >>= 1) v += __shfl_xor(v, off);
  int wave = threadIdx.x >> 6, lane = threadIdx.x & 63;
  if (lane == 0) red[wave] = v;
  __syncthreads();
  float s = 0.0f;
  #pragma unroll
  for (int w = 0; w < 16; ++w) s += red[w];
  __syncthreads();
  return s;
}

__global__ __launch_bounds__(1024) void finalize_kernel(
    const float* __restrict__ log_prior, const float* __restrict__ resp_g,
    float* __restrict__ out_prior) {
  __shared__ float red[16];
  int t = threadIdx.x;
  float lp = log_prior[t];
  float rs = resp_g[t];

  float m1 = block_max_1024(lp, red);
  float e1 = __expf(lp - m1);
  float s1 = block_sum_1024(e1, red);

  float m2 = block_max_1024(rs, red);
  float e2 = __expf(rs - m2);
  float s2 = block_sum_1024(e2, red);

  out_prior[t] = DECAY * (e1 / s1) + (1.0f - DECAY) * (e2 / s2);
}

extern "C" void kernel_launch(void* const* d_in, const int* in_sizes, int n_in,
                              void* d_out, int out_size, void* d_ws, size_t ws_size,
                              hipStream_t stream) {
  const float* slots     = (const float*)d_in[0];
  const float* mu        = (const float*)d_in[1];
  const float* log_sigma = (const float*)d_in[2];
  const float* log_prior = (const float*)d_in[3];
  const float* z         = (const float*)d_in[4];

  float* out       = (float*)d_out;
  float* out_slots = out;                       // [BS*DD]
  float* out_ll    = out + (size_t)BS*DD;       // [BS]
  float* out_prior = out + (size_t)BS*DD + BS;  // [KK]
  float* ws        = (float*)d_ws;

  hipMemsetAsync(ws + RESP_OFF, 0, KK*sizeof(float), stream);
  prep_kernel<<<KK, 64, 0, stream>>>(mu, log_sigma, ws);
  main_kernel<<<NBLK, NTHR, 0, stream>>>(slots, mu, z, ws, out_slots, out_ll,
                                         ws + RESP_OFF);
  finalize_kernel<<<1, 1024, 0, stream>>>(log_prior, ws + RESP_OFF, out_prior);
}